// Round 8
// baseline (342.038 us; speedup 1.0000x reference)
//
#include <hip/hip_runtime.h>

#define NH 8
#define HD 32
#define SUMP 16
#define LQ 4096
#define BS 4
#define LV 8500
#define NQ (BS * LQ)   // 16384
#define MV (BS * LV)   // 34000

typedef float f32x4 __attribute__((ext_vector_type(4)));
typedef _Float16 f16x8 __attribute__((ext_vector_type(8)));

// ---------- prep: weights -> fp16 fragment-linear; bias concat ----------
// frag-linear: unit block (T = n>>4, C = k>>5) of 512 fp16 at offset (T*8+C)*512;
// within: lane16 = (n&15) + 16*((k>>3)&3) at lane16*8, elem = k&7.
__global__ __launch_bounds__(256) void prep_kernel(
    const float* __restrict__ Wv, const float* __restrict__ Woff,
    const float* __restrict__ Wattn, const float* __restrict__ Wo,
    const float* __restrict__ boff, const float* __restrict__ battn,
    _Float16* __restrict__ WtVf, _Float16* __restrict__ WtOAf,
    _Float16* __restrict__ WtOf, float* __restrict__ biasOA)
{
    int g = blockIdx.x * 256 + threadIdx.x;    // 0..229375
    int gl; _Float16* dst; int which;
    if (g < 65536)       { gl = g;          dst = WtVf;  which = 0; }
    else if (g < 163840) { gl = g - 65536;  dst = WtOAf; which = 1; }
    else                 { gl = g - 163840; dst = WtOf;  which = 2; }
    int e = gl & 7, m16 = (gl >> 3) & 15, q = (gl >> 7) & 3, C = (gl >> 9) & 7, T = gl >> 12;
    int n = T * 16 + m16, k = C * 32 + q * 8 + e;
    float w;
    if (which == 0)      w = Wv[k * 256 + n];
    else if (which == 1) w = (n < 256) ? Woff[k * 256 + n] : Wattn[k * 128 + (n - 256)];
    else                 w = Wo[k * 256 + n];
    dst[gl] = (_Float16)w;
    if (blockIdx.x == 0) biasOA[threadIdx.x] = boff[threadIdx.x];
    if (blockIdx.x == 1 && threadIdx.x < 128) biasOA[256 + threadIdx.x] = battn[threadIdx.x];
}

// ---------- GEMM: LDS-A (XOR swizzle, conflict-free) + frag-linear global B ----------
// Block 128x128, 4 waves 2x2, wave tile 64x64, K=256, BK=32, fp16 MFMA.
template <bool V_MODE, bool A_F16>
__device__ __forceinline__ void gemm_body(
    const float* __restrict__ A32, const _Float16* __restrict__ A16,
    const _Float16* __restrict__ Bf,
    const float* __restrict__ bias, void* __restrict__ Cv,
    int M, int N, int mb, int nb, _Float16* As /* 2*4096 fp16 */)
{
    const int t = threadIdx.x;
    const int wave = t >> 6, lane = t & 63;
    const int quad = lane >> 4, l16 = lane & 15;
    const int mbase = mb * 128 + (wave & 1) * 64;
    const int ntile0 = nb * 8 + (wave >> 1) * 4;

    const int srow = t >> 2, skq = t & 3;
    int gm0 = mb * 128 + srow;        if (gm0 > M - 1) gm0 = M - 1;
    int gm1 = mb * 128 + srow + 64;   if (gm1 > M - 1) gm1 = M - 1;
    const float* ap0 = A32 ? A32 + (size_t)gm0 * 256 + skq * 8 : nullptr;
    const float* ap1 = A32 ? A32 + (size_t)gm1 * 256 + skq * 8 : nullptr;
    const _Float16* hp0 = A16 ? A16 + (size_t)gm0 * 256 + skq * 8 : nullptr;
    const _Float16* hp1 = A16 ? A16 + (size_t)gm1 * 256 + skq * 8 : nullptr;
    const int slot0 = (((srow >> 4)) * 64 + skq * 16 + ((srow & 15) ^ skq)) * 8;
    const int slot1 = ((((srow + 64) >> 4)) * 64 + skq * 16 + ((srow & 15) ^ skq)) * 8;

    const _Float16* bp[4];
    #pragma unroll
    for (int ni = 0; ni < 4; ++ni)
        bp[ni] = Bf + (size_t)(ntile0 + ni) * 4096 + lane * 8;

    float a0[8], a1[8];
    f16x8 a0h, a1h;
    f16x8 bcur[4], bnxt[4];
    f32x4 acc[4][4] = {};

    if (A_F16) {
        a0h = *(const f16x8*)(hp0);
        a1h = *(const f16x8*)(hp1);
    } else {
        *(float4*)(a0 + 0) = *(const float4*)(ap0 + 0);
        *(float4*)(a0 + 4) = *(const float4*)(ap0 + 4);
        *(float4*)(a1 + 0) = *(const float4*)(ap1 + 0);
        *(float4*)(a1 + 4) = *(const float4*)(ap1 + 4);
    }
    #pragma unroll
    for (int ni = 0; ni < 4; ++ni) bcur[ni] = *(const f16x8*)(bp[ni]);

    #pragma unroll
    for (int k = 0; k < 8; ++k) {
        _Float16* buf = As + (k & 1) * 4096;
        f16x8 c0, c1;
        if (A_F16) { c0 = a0h; c1 = a1h; }
        else {
            #pragma unroll
            for (int j = 0; j < 8; ++j) { c0[j] = (_Float16)a0[j]; c1[j] = (_Float16)a1[j]; }
        }
        *(f16x8*)(buf + slot0) = c0;
        *(f16x8*)(buf + slot1) = c1;
        __syncthreads();
        if (k < 7) {
            const int k0 = (k + 1) * 32;
            if (A_F16) {
                a0h = *(const f16x8*)(hp0 + k0);
                a1h = *(const f16x8*)(hp1 + k0);
            } else {
                *(float4*)(a0 + 0) = *(const float4*)(ap0 + k0);
                *(float4*)(a0 + 4) = *(const float4*)(ap0 + k0 + 4);
                *(float4*)(a1 + 0) = *(const float4*)(ap1 + k0);
                *(float4*)(a1 + 4) = *(const float4*)(ap1 + k0 + 4);
            }
            #pragma unroll
            for (int ni = 0; ni < 4; ++ni) bnxt[ni] = *(const f16x8*)(bp[ni] + (k + 1) * 512);
        }
        f16x8 af[4];
        #pragma unroll
        for (int mi = 0; mi < 4; ++mi)
            af[mi] = *(const f16x8*)(buf + (((wave & 1) * 4 + mi) * 64 + quad * 16 + (l16 ^ quad)) * 8);
        #pragma unroll
        for (int mi = 0; mi < 4; ++mi)
            #pragma unroll
            for (int ni = 0; ni < 4; ++ni)
                acc[mi][ni] = __builtin_amdgcn_mfma_f32_16x16x32_f16(af[mi], bcur[ni], acc[mi][ni], 0, 0, 0);
        #pragma unroll
        for (int ni = 0; ni < 4; ++ni) bcur[ni] = bnxt[ni];
    }

    // epilogue: C/D col = l16, row = quad*4+r
    if (V_MODE) {
        #pragma unroll
        for (int mi = 0; mi < 4; ++mi) {
            int mq = mbase + mi * 16 + quad * 4;
            size_t rb[4]; int vld[4];
            #pragma unroll
            for (int r = 0; r < 4; ++r) {
                int m = mq + r;
                vld[r] = (m < M);
                int b = m / LV; int pos = m - b * LV;
                rb[r] = ((size_t)b * NH * LV + pos) * 32;
            }
            #pragma unroll
            for (int ni = 0; ni < 4; ++ni) {
                int n = (ntile0 + ni) * 16 + l16;
                float bv = bias[n];
                int h = n >> 5, d = n & 31;
                size_t ho = (size_t)h * (LV * 32) + d;
                #pragma unroll
                for (int r = 0; r < 4; ++r)
                    if (vld[r]) ((_Float16*)Cv)[rb[r] + ho] = (_Float16)(acc[mi][ni][r] + bv);
            }
        }
    } else {
        #pragma unroll
        for (int ni = 0; ni < 4; ++ni) {
            int n = (ntile0 + ni) * 16 + l16;
            float bv = bias[n];
            #pragma unroll
            for (int mi = 0; mi < 4; ++mi) {
                int mq = mbase + mi * 16 + quad * 4;
                #pragma unroll
                for (int r = 0; r < 4; ++r)
                    ((float*)Cv)[(size_t)(mq + r) * N + n] = acc[mi][ni][r] + bv;
            }
        }
    }
}

__global__ __launch_bounds__(256) void gemm_dual_kernel(
    const float* __restrict__ value, const _Float16* __restrict__ WtVf,
    const float* __restrict__ b_v, _Float16* __restrict__ v_f16,
    const float* __restrict__ query, const _Float16* __restrict__ WtOAf,
    const float* __restrict__ biasOA, float* __restrict__ oa)
{
    __shared__ __align__(16) _Float16 As[2 * 4096];
    int bid = blockIdx.x;
    if (bid < 532) {          // V: 266 mb x 2 nb
        gemm_body<true, false>(value, nullptr, WtVf, b_v, v_f16, MV, 256, bid % 266, bid / 266, As);
    } else {                  // OA: 128 mb x 3 nb
        int q = bid - 532;
        gemm_body<false, false>(query, nullptr, WtOAf, biasOA, oa, NQ, 384, q % 128, q / 128, As);
    }
}

__global__ __launch_bounds__(256) void gemm_o_kernel(
    const _Float16* __restrict__ mid, const _Float16* __restrict__ WtOf,
    const float* __restrict__ b_o, float* __restrict__ out)
{
    __shared__ __align__(16) _Float16 As[2 * 4096];
    gemm_body<false, true>(nullptr, mid, WtOf, b_o, out, NQ, 256,
                           blockIdx.x & 127, blockIdx.x >> 7, As);
}

// ---------- sampling: gather-only, high occupancy ----------
// QPB=4 (4096 blocks). Lane = pg(1b)|h(3b)|dv2(2b): each lane 8 points x 4 corners
// of 16B fp16 loads; pg halves combined via shfl_xor(32).
__global__ __launch_bounds__(256, 6) void sample_kernel(
    const _Float16* __restrict__ v,          // [b][h][LV][32] fp16
    const float* __restrict__ oa,            // [NQ][384]: 0..255 offsets, 256..383 logits
    const float* __restrict__ refp,          // [NQ][4]
    _Float16* __restrict__ mid)              // [NQ][256] fp16
{
    const int row0 = blockIdx.x * 4;
    const int t = threadIdx.x;
    const int wave = t >> 6, lane = t & 63;

    __shared__ __align__(16) char smem[13312];
    float*  s_lx  = (float*)smem;                 // [4][128]  (union A: 6144 B)
    float*  s_ly  = (float*)(smem + 2048);
    float*  s_raw = (float*)(smem + 4096);
    int2*   s_pk  = (int2*)smem;                  // [4*8][17] (union B: 13056 B)
    float4* s_w4  = (float4*)(smem + 4352);
    float*  s_mx  = (float*)(smem + 13056);       // [32]
    float*  s_is  = (float*)(smem + 13184);       // [32]

    // --- P1: locations + raw logits (512 entries, 2/thread) ---
    #pragma unroll
    for (int it = 0; it < 2; ++it) {
        int i = t + it * 256;
        int q = i >> 7, e = i & 127;          // e = h*16 + p
        int row = row0 + q;
        float4 r4 = *(const float4*)(refp + (size_t)row * 4);
        float2 o2 = *(const float2*)(oa + (size_t)row * 384 + e * 2);
        s_lx[q * 128 + e]  = r4.x + o2.x * 0.125f * r4.z;
        s_ly[q * 128 + e]  = r4.y + o2.y * 0.125f * r4.w;
        s_raw[q * 128 + e] = oa[(size_t)row * 384 + 256 + e];
    }
    __syncthreads();
    // --- P2: softmax stats, one (q,h) per thread ---
    if (t < 32) {
        int q = t >> 3, h = t & 7;
        float mx = -1e30f;
        #pragma unroll
        for (int p = 0; p < SUMP; ++p) mx = fmaxf(mx, s_raw[q * 128 + h * 16 + p]);
        float sm = 0.f;
        #pragma unroll
        for (int p = 0; p < SUMP; ++p) sm += __expf(s_raw[q * 128 + h * 16 + p] - mx);
        s_mx[t] = mx; s_is[t] = 1.f / sm;
    }
    __syncthreads();
    // --- P3: corner weights + packed offsets to regs, then overlay store ---
    int2 r_pk[2];
    float4 r_w4[2];
    #pragma unroll
    for (int it = 0; it < 2; ++it) {
        int i = t + it * 256;
        int q = i >> 7, e = i & 127, h = e >> 4, p = e & 15, l = p >> 2;
        int Wl = 80 >> l;
        int vst = (l == 0) ? 0 : (l == 1) ? 6400 : (l == 2) ? 8000 : 8400;
        float w = __expf(s_raw[q * 128 + e] - s_mx[q * 8 + h]) * s_is[q * 8 + h];
        float x = s_lx[q * 128 + e] * Wl - 0.5f;
        float y = s_ly[q * 128 + e] * Wl - 0.5f;
        float x0f = floorf(x), y0f = floorf(y);
        float lx = x - x0f, ly = y - y0f;
        int x0 = (int)x0f, y0 = (int)y0f;
        int x1 = x0 + 1, y1 = y0 + 1;
        float mx0 = (x0 >= 0 && x0 < Wl) ? 1.f : 0.f;
        float mx1 = (x1 >= 0 && x1 < Wl) ? 1.f : 0.f;
        float my0 = (y0 >= 0 && y0 < Wl) ? 1.f : 0.f;
        float my1 = (y1 >= 0 && y1 < Wl) ? 1.f : 0.f;
        int cx0 = min(max(x0, 0), Wl - 1), cx1 = min(max(x1, 0), Wl - 1);
        int cy0 = min(max(y0, 0), Wl - 1), cy1 = min(max(y1, 0), Wl - 1);
        r_pk[it].x = (vst + cy0 * Wl + cx0) * 64;
        r_pk[it].y = ((cx1 - cx0) * 64) | (((cy1 - cy0) * Wl * 64) << 16);
        float4 w4;
        w4.x = w * (1.f - lx) * (1.f - ly) * mx0 * my0;
        w4.y = w * lx * (1.f - ly) * mx1 * my0;
        w4.z = w * (1.f - lx) * ly * mx0 * my1;
        w4.w = w * lx * ly * mx1 * my1;
        r_w4[it] = w4;
    }
    __syncthreads();   // union-A reads done before overlay write
    #pragma unroll
    for (int it = 0; it < 2; ++it) {
        int i = t + it * 256;
        int q = i >> 7, e = i & 127, h = e >> 4, p = e & 15;
        int s = (q * 8 + h) * 17 + p;
        s_pk[s] = r_pk[it]; s_w4[s] = r_w4[it];
    }
    __syncthreads();
    // --- P4: gather. wave = query; lane = pg|h|dv2; 8 points/lane ---
    {
        const int pg = lane >> 5, hh = (lane >> 2) & 7, dv2 = lane & 3;
        const int q = wave;
        const int row = row0 + q;
        const int b = row >> 12;              // LQ = 4096
        const char* vb = (const char*)v + ((size_t)(b * NH + hh) * LV) * 64 + dv2 * 16;
        float acc8[8] = {};
        #pragma unroll
        for (int j = 0; j < 8; ++j) {
            int p = pg * 8 + j;
            int s = (q * 8 + hh) * 17 + p;
            int2 pk = s_pk[s];
            float4 w4 = s_w4[s];
            int dx = pk.y & 0xffff, dy = pk.y >> 16;
            f16x8 g00 = *(const f16x8*)(vb + pk.x);
            f16x8 g01 = *(const f16x8*)(vb + pk.x + dx);
            f16x8 g10 = *(const f16x8*)(vb + pk.x + dy);
            f16x8 g11 = *(const f16x8*)(vb + pk.x + dx + dy);
            #pragma unroll
            for (int c = 0; c < 8; ++c)
                acc8[c] += w4.x * (float)g00[c] + w4.y * (float)g01[c]
                         + w4.z * (float)g10[c] + w4.w * (float)g11[c];
        }
        #pragma unroll
        for (int c = 0; c < 8; ++c) acc8[c] += __shfl_xor(acc8[c], 32, 64);
        if (pg == 0) {
            f16x8 m8;
            #pragma unroll
            for (int c = 0; c < 8; ++c) m8[c] = (_Float16)acc8[c];
            *(f16x8*)(mid + (size_t)row * 256 + hh * 32 + dv2 * 8) = m8;
        }
    }
}

extern "C" void kernel_launch(void* const* d_in, const int* in_sizes, int n_in,
                              void* d_out, int out_size, void* d_ws, size_t ws_size,
                              hipStream_t stream) {
    const float* query  = (const float*)d_in[0];   // [4,4096,256]
    const float* refp   = (const float*)d_in[1];   // [4,4096,1,4]
    const float* value  = (const float*)d_in[2];   // [4,8500,256]
    const float* W_off  = (const float*)d_in[3];   // [256,256]
    const float* b_off  = (const float*)d_in[4];   // [256]
    const float* W_attn = (const float*)d_in[5];   // [256,128]
    const float* b_attn = (const float*)d_in[6];   // [128]
    const float* W_v    = (const float*)d_in[7];   // [256,256]
    const float* b_v    = (const float*)d_in[8];   // [256]
    const float* W_o    = (const float*)d_in[9];   // [256,256]
    const float* b_o    = (const float*)d_in[10];  // [256]

    char* ws = (char*)d_ws;
    _Float16* v_f16  = (_Float16*)(ws + 0);               // 17,408,000 B
    float*    oa_f32 = (float*)(ws + 17408000);           // 25,165,824 B
    _Float16* mid    = (_Float16*)(ws + 42573824);        //  8,388,608 B
    _Float16* WtVf   = (_Float16*)(ws + 50962432);        //    131,072 B
    _Float16* WtOAf  = (_Float16*)(ws + 51093504);        //    196,608 B
    _Float16* WtOf   = (_Float16*)(ws + 51290112);        //    131,072 B
    float*    biasOA = (float*)(ws + 51421184);           //      1,536 B

    prep_kernel<<<896, 256, 0, stream>>>(W_v, W_off, W_attn, W_o, b_off, b_attn,
                                         WtVf, WtOAf, WtOf, biasOA);
    gemm_dual_kernel<<<916, 256, 0, stream>>>(
        value, WtVf, b_v, v_f16, query, WtOAf, biasOA, oa_f32);
    sample_kernel<<<NQ / 4, 256, 0, stream>>>(v_f16, oa_f32, refp, mid);
    gemm_o_kernel<<<256, 256, 0, stream>>>(mid, WtOf, b_o, (float*)d_out);
}

// Round 9
// 211.507 us; speedup vs baseline: 1.6171x; 1.6171x over previous
//
#include <hip/hip_runtime.h>

#define NH 8
#define HD 32
#define SUMP 16
#define LQ 4096
#define BS 4
#define LV 8500
#define NQ (BS * LQ)   // 16384
#define MV (BS * LV)   // 34000

typedef float f32x4 __attribute__((ext_vector_type(4)));
typedef _Float16 f16x8 __attribute__((ext_vector_type(8)));

// ---------- prep: weights -> fp16 fragment-linear; bias concat ----------
// frag-linear: unit block (T = n>>4, C = k>>5) of 512 fp16 at offset (T*8+C)*512;
// within: lane16 = (n&15) + 16*((k>>3)&3) at lane16*8, elem = k&7.
__global__ __launch_bounds__(256) void prep_kernel(
    const float* __restrict__ Wv, const float* __restrict__ Woff,
    const float* __restrict__ Wattn, const float* __restrict__ Wo,
    const float* __restrict__ boff, const float* __restrict__ battn,
    _Float16* __restrict__ WtVf, _Float16* __restrict__ WtOAf,
    _Float16* __restrict__ WtOf, float* __restrict__ biasOA)
{
    int g = blockIdx.x * 256 + threadIdx.x;    // 0..229375
    int gl; _Float16* dst; int which;
    if (g < 65536)       { gl = g;          dst = WtVf;  which = 0; }
    else if (g < 163840) { gl = g - 65536;  dst = WtOAf; which = 1; }
    else                 { gl = g - 163840; dst = WtOf;  which = 2; }
    int e = gl & 7, m16 = (gl >> 3) & 15, q = (gl >> 7) & 3, C = (gl >> 9) & 7, T = gl >> 12;
    int n = T * 16 + m16, k = C * 32 + q * 8 + e;
    float w;
    if (which == 0)      w = Wv[k * 256 + n];
    else if (which == 1) w = (n < 256) ? Woff[k * 256 + n] : Wattn[k * 128 + (n - 256)];
    else                 w = Wo[k * 256 + n];
    dst[gl] = (_Float16)w;
    if (blockIdx.x == 0) biasOA[threadIdx.x] = boff[threadIdx.x];
    if (blockIdx.x == 1 && threadIdx.x < 128) biasOA[256 + threadIdx.x] = battn[threadIdx.x];
}

// ---------- GEMM: LDS-A (XOR swizzle) + frag-linear global B ----------
// Block 128 x (NI*32), 4 waves 2x2, wave tile 64 x (NI*16), K=256, BK=32, fp16 MFMA.
template <int NI, bool V_MODE, bool A_F16>
__device__ __forceinline__ void gemm_body(
    const float* __restrict__ A32, const _Float16* __restrict__ A16,
    const _Float16* __restrict__ Bf,
    const float* __restrict__ bias, void* __restrict__ Cv,
    int M, int N, int mb, int nb, _Float16* As /* 2*4096 fp16 */)
{
    const int t = threadIdx.x;
    const int wave = t >> 6, lane = t & 63;
    const int quad = lane >> 4, l16 = lane & 15;
    const int mbase = mb * 128 + (wave & 1) * 64;
    const int ntile0 = nb * (2 * NI) + (wave >> 1) * NI;

    const int srow = t >> 2, skq = t & 3;
    int gm0 = mb * 128 + srow;        if (gm0 > M - 1) gm0 = M - 1;
    int gm1 = mb * 128 + srow + 64;   if (gm1 > M - 1) gm1 = M - 1;
    const float* ap0 = A32 ? A32 + (size_t)gm0 * 256 + skq * 8 : nullptr;
    const float* ap1 = A32 ? A32 + (size_t)gm1 * 256 + skq * 8 : nullptr;
    const _Float16* hp0 = A16 ? A16 + (size_t)gm0 * 256 + skq * 8 : nullptr;
    const _Float16* hp1 = A16 ? A16 + (size_t)gm1 * 256 + skq * 8 : nullptr;
    const int slot0 = (((srow >> 4)) * 64 + skq * 16 + ((srow & 15) ^ skq)) * 8;
    const int slot1 = ((((srow + 64) >> 4)) * 64 + skq * 16 + ((srow & 15) ^ skq)) * 8;

    const _Float16* bp[NI];
    #pragma unroll
    for (int ni = 0; ni < NI; ++ni)
        bp[ni] = Bf + (size_t)(ntile0 + ni) * 4096 + lane * 8;

    float a0[8], a1[8];
    f16x8 a0h, a1h;
    f16x8 bcur[NI], bnxt[NI];
    f32x4 acc[4][NI] = {};

    if (A_F16) {
        a0h = *(const f16x8*)(hp0);
        a1h = *(const f16x8*)(hp1);
    } else {
        *(float4*)(a0 + 0) = *(const float4*)(ap0 + 0);
        *(float4*)(a0 + 4) = *(const float4*)(ap0 + 4);
        *(float4*)(a1 + 0) = *(const float4*)(ap1 + 0);
        *(float4*)(a1 + 4) = *(const float4*)(ap1 + 4);
    }
    #pragma unroll
    for (int ni = 0; ni < NI; ++ni) bcur[ni] = *(const f16x8*)(bp[ni]);

    #pragma unroll
    for (int k = 0; k < 8; ++k) {
        _Float16* buf = As + (k & 1) * 4096;
        f16x8 c0, c1;
        if (A_F16) { c0 = a0h; c1 = a1h; }
        else {
            #pragma unroll
            for (int j = 0; j < 8; ++j) { c0[j] = (_Float16)a0[j]; c1[j] = (_Float16)a1[j]; }
        }
        *(f16x8*)(buf + slot0) = c0;
        *(f16x8*)(buf + slot1) = c1;
        __syncthreads();
        if (k < 7) {
            const int k0 = (k + 1) * 32;
            if (A_F16) {
                a0h = *(const f16x8*)(hp0 + k0);
                a1h = *(const f16x8*)(hp1 + k0);
            } else {
                *(float4*)(a0 + 0) = *(const float4*)(ap0 + k0);
                *(float4*)(a0 + 4) = *(const float4*)(ap0 + k0 + 4);
                *(float4*)(a1 + 0) = *(const float4*)(ap1 + k0);
                *(float4*)(a1 + 4) = *(const float4*)(ap1 + k0 + 4);
            }
            #pragma unroll
            for (int ni = 0; ni < NI; ++ni) bnxt[ni] = *(const f16x8*)(bp[ni] + (k + 1) * 512);
        }
        f16x8 af[4];
        #pragma unroll
        for (int mi = 0; mi < 4; ++mi)
            af[mi] = *(const f16x8*)(buf + (((wave & 1) * 4 + mi) * 64 + quad * 16 + (l16 ^ quad)) * 8);
        #pragma unroll
        for (int mi = 0; mi < 4; ++mi)
            #pragma unroll
            for (int ni = 0; ni < NI; ++ni)
                acc[mi][ni] = __builtin_amdgcn_mfma_f32_16x16x32_f16(af[mi], bcur[ni], acc[mi][ni], 0, 0, 0);
        #pragma unroll
        for (int ni = 0; ni < NI; ++ni) bcur[ni] = bnxt[ni];
    }

    // epilogue: C/D col = l16, row = quad*4+r
    if (V_MODE) {
        #pragma unroll
        for (int mi = 0; mi < 4; ++mi) {
            int mq = mbase + mi * 16 + quad * 4;
            size_t rb[4]; int vld[4];
            #pragma unroll
            for (int r = 0; r < 4; ++r) {
                int m = mq + r;
                vld[r] = (m < M);
                int b = m / LV; int pos = m - b * LV;
                rb[r] = ((size_t)b * NH * LV + pos) * 32;
            }
            #pragma unroll
            for (int ni = 0; ni < NI; ++ni) {
                int n = (ntile0 + ni) * 16 + l16;
                float bv = bias[n];
                int h = n >> 5, d = n & 31;
                size_t ho = (size_t)h * (LV * 32) + d;
                #pragma unroll
                for (int r = 0; r < 4; ++r)
                    if (vld[r]) ((_Float16*)Cv)[rb[r] + ho] = (_Float16)(acc[mi][ni][r] + bv);
            }
        }
    } else {
        #pragma unroll
        for (int ni = 0; ni < NI; ++ni) {
            int n = (ntile0 + ni) * 16 + l16;
            float bv = bias[n];
            #pragma unroll
            for (int mi = 0; mi < 4; ++mi) {
                int mq = mbase + mi * 16 + quad * 4;
                #pragma unroll
                for (int r = 0; r < 4; ++r)
                    ((float*)Cv)[(size_t)(mq + r) * N + n] = acc[mi][ni][r] + bv;
            }
        }
    }
}

__global__ __launch_bounds__(256) void gemm_dual_kernel(
    const float* __restrict__ value, const _Float16* __restrict__ WtVf,
    const float* __restrict__ b_v, _Float16* __restrict__ v_f16,
    const float* __restrict__ query, const _Float16* __restrict__ WtOAf,
    const float* __restrict__ biasOA, float* __restrict__ oa)
{
    __shared__ __align__(16) _Float16 As[2 * 4096];
    int bid = blockIdx.x;
    if (bid < 1064) {         // V: 266 mb x 4 nb (tile 128x64)
        gemm_body<2, true, false>(value, nullptr, WtVf, b_v, v_f16, MV, 256,
                                  bid % 266, bid / 266, As);
    } else {                  // OA: 128 mb x 6 nb (tile 128x64)
        int q = bid - 1064;
        gemm_body<2, false, false>(query, nullptr, WtOAf, biasOA, oa, NQ, 384,
                                   q % 128, q / 128, As);
    }
}

__global__ __launch_bounds__(256) void gemm_o_kernel(
    const _Float16* __restrict__ mid, const _Float16* __restrict__ WtOf,
    const float* __restrict__ b_o, float* __restrict__ out)
{
    __shared__ __align__(16) _Float16 As[2 * 4096];
    gemm_body<2, false, true>(nullptr, mid, WtOf, b_o, out, NQ, 256,
                              blockIdx.x & 127, blockIdx.x >> 7, As);
}

// ---------- sampling: gather-only ----------
// QPB=4 (4096 blocks). Lane = pg(1b)|h(3b)|dv2(2b): each lane 8 points x 4 corners
// of 16B fp16 loads; pg halves combined via shfl_xor(32).
// launch_bounds (256,4): VGPR cap 128 — enough in-flight corner loads, NO spill
// (R7's (256,6) forced VGPR=40 -> 550 MB scratch spill traffic, 205us).
__global__ __launch_bounds__(256, 4) void sample_kernel(
    const _Float16* __restrict__ v,          // [b][h][LV][32] fp16
    const float* __restrict__ oa,            // [NQ][384]: 0..255 offsets, 256..383 logits
    const float* __restrict__ refp,          // [NQ][4]
    _Float16* __restrict__ mid)              // [NQ][256] fp16
{
    const int row0 = blockIdx.x * 4;
    const int t = threadIdx.x;
    const int wave = t >> 6, lane = t & 63;

    __shared__ __align__(16) char smem[13312];
    float*  s_lx  = (float*)smem;                 // [4][128]  (union A: 6144 B)
    float*  s_ly  = (float*)(smem + 2048);
    float*  s_raw = (float*)(smem + 4096);
    int2*   s_pk  = (int2*)smem;                  // [4*8][17] (union B: 13056 B)
    float4* s_w4  = (float4*)(smem + 4352);
    float*  s_mx  = (float*)(smem + 13056);       // [32]
    float*  s_is  = (float*)(smem + 13184);       // [32]

    // --- P1: locations + raw logits (512 entries, 2/thread) ---
    #pragma unroll
    for (int it = 0; it < 2; ++it) {
        int i = t + it * 256;
        int q = i >> 7, e = i & 127;          // e = h*16 + p
        int row = row0 + q;
        float4 r4 = *(const float4*)(refp + (size_t)row * 4);
        float2 o2 = *(const float2*)(oa + (size_t)row * 384 + e * 2);
        s_lx[q * 128 + e]  = r4.x + o2.x * 0.125f * r4.z;
        s_ly[q * 128 + e]  = r4.y + o2.y * 0.125f * r4.w;
        s_raw[q * 128 + e] = oa[(size_t)row * 384 + 256 + e];
    }
    __syncthreads();
    // --- P2: softmax stats, one (q,h) per thread ---
    if (t < 32) {
        int q = t >> 3, h = t & 7;
        float mx = -1e30f;
        #pragma unroll
        for (int p = 0; p < SUMP; ++p) mx = fmaxf(mx, s_raw[q * 128 + h * 16 + p]);
        float sm = 0.f;
        #pragma unroll
        for (int p = 0; p < SUMP; ++p) sm += __expf(s_raw[q * 128 + h * 16 + p] - mx);
        s_mx[t] = mx; s_is[t] = 1.f / sm;
    }
    __syncthreads();
    // --- P3: corner weights + packed offsets to regs, then overlay store ---
    int2 r_pk[2];
    float4 r_w4[2];
    #pragma unroll
    for (int it = 0; it < 2; ++it) {
        int i = t + it * 256;
        int q = i >> 7, e = i & 127, h = e >> 4, p = e & 15, l = p >> 2;
        int Wl = 80 >> l;
        int vst = (l == 0) ? 0 : (l == 1) ? 6400 : (l == 2) ? 8000 : 8400;
        float w = __expf(s_raw[q * 128 + e] - s_mx[q * 8 + h]) * s_is[q * 8 + h];
        float x = s_lx[q * 128 + e] * Wl - 0.5f;
        float y = s_ly[q * 128 + e] * Wl - 0.5f;
        float x0f = floorf(x), y0f = floorf(y);
        float lx = x - x0f, ly = y - y0f;
        int x0 = (int)x0f, y0 = (int)y0f;
        int x1 = x0 + 1, y1 = y0 + 1;
        float mx0 = (x0 >= 0 && x0 < Wl) ? 1.f : 0.f;
        float mx1 = (x1 >= 0 && x1 < Wl) ? 1.f : 0.f;
        float my0 = (y0 >= 0 && y0 < Wl) ? 1.f : 0.f;
        float my1 = (y1 >= 0 && y1 < Wl) ? 1.f : 0.f;
        int cx0 = min(max(x0, 0), Wl - 1), cx1 = min(max(x1, 0), Wl - 1);
        int cy0 = min(max(y0, 0), Wl - 1), cy1 = min(max(y1, 0), Wl - 1);
        r_pk[it].x = (vst + cy0 * Wl + cx0) * 64;
        r_pk[it].y = ((cx1 - cx0) * 64) | (((cy1 - cy0) * Wl * 64) << 16);
        float4 w4;
        w4.x = w * (1.f - lx) * (1.f - ly) * mx0 * my0;
        w4.y = w * lx * (1.f - ly) * mx1 * my0;
        w4.z = w * (1.f - lx) * ly * mx0 * my1;
        w4.w = w * lx * ly * mx1 * my1;
        r_w4[it] = w4;
    }
    __syncthreads();   // union-A reads done before overlay write
    #pragma unroll
    for (int it = 0; it < 2; ++it) {
        int i = t + it * 256;
        int q = i >> 7, e = i & 127, h = e >> 4, p = e & 15;
        int s = (q * 8 + h) * 17 + p;
        s_pk[s] = r_pk[it]; s_w4[s] = r_w4[it];
    }
    __syncthreads();
    // --- P4: gather. wave = query; lane = pg|h|dv2; 8 points/lane ---
    {
        const int pg = lane >> 5, hh = (lane >> 2) & 7, dv2 = lane & 3;
        const int q = wave;
        const int row = row0 + q;
        const int b = row >> 12;              // LQ = 4096
        const char* vb = (const char*)v + ((size_t)(b * NH + hh) * LV) * 64 + dv2 * 16;
        float acc8[8] = {};
        #pragma unroll
        for (int j = 0; j < 8; ++j) {
            int p = pg * 8 + j;
            int s = (q * 8 + hh) * 17 + p;
            int2 pk = s_pk[s];
            float4 w4 = s_w4[s];
            int dx = pk.y & 0xffff, dy = pk.y >> 16;
            f16x8 g00 = *(const f16x8*)(vb + pk.x);
            f16x8 g01 = *(const f16x8*)(vb + pk.x + dx);
            f16x8 g10 = *(const f16x8*)(vb + pk.x + dy);
            f16x8 g11 = *(const f16x8*)(vb + pk.x + dx + dy);
            #pragma unroll
            for (int c = 0; c < 8; ++c)
                acc8[c] += w4.x * (float)g00[c] + w4.y * (float)g01[c]
                         + w4.z * (float)g10[c] + w4.w * (float)g11[c];
        }
        #pragma unroll
        for (int c = 0; c < 8; ++c) acc8[c] += __shfl_xor(acc8[c], 32, 64);
        if (pg == 0) {
            f16x8 m8;
            #pragma unroll
            for (int c = 0; c < 8; ++c) m8[c] = (_Float16)acc8[c];
            *(f16x8*)(mid + (size_t)row * 256 + hh * 32 + dv2 * 8) = m8;
        }
    }
}

extern "C" void kernel_launch(void* const* d_in, const int* in_sizes, int n_in,
                              void* d_out, int out_size, void* d_ws, size_t ws_size,
                              hipStream_t stream) {
    const float* query  = (const float*)d_in[0];   // [4,4096,256]
    const float* refp   = (const float*)d_in[1];   // [4,4096,1,4]
    const float* value  = (const float*)d_in[2];   // [4,8500,256]
    const float* W_off  = (const float*)d_in[3];   // [256,256]
    const float* b_off  = (const float*)d_in[4];   // [256]
    const float* W_attn = (const float*)d_in[5];   // [256,128]
    const float* b_attn = (const float*)d_in[6];   // [128]
    const float* W_v    = (const float*)d_in[7];   // [256,256]
    const float* b_v    = (const float*)d_in[8];   // [256]
    const float* W_o    = (const float*)d_in[9];   // [256,256]
    const float* b_o    = (const float*)d_in[10];  // [256]

    char* ws = (char*)d_ws;
    _Float16* v_f16  = (_Float16*)(ws + 0);               // 17,408,000 B
    float*    oa_f32 = (float*)(ws + 17408000);           // 25,165,824 B
    _Float16* mid    = (_Float16*)(ws + 42573824);        //  8,388,608 B
    _Float16* WtVf   = (_Float16*)(ws + 50962432);        //    131,072 B
    _Float16* WtOAf  = (_Float16*)(ws + 51093504);        //    196,608 B
    _Float16* WtOf   = (_Float16*)(ws + 51290112);        //    131,072 B
    float*    biasOA = (float*)(ws + 51421184);           //      1,536 B

    prep_kernel<<<896, 256, 0, stream>>>(W_v, W_off, W_attn, W_o, b_off, b_attn,
                                         WtVf, WtOAf, WtOf, biasOA);
    gemm_dual_kernel<<<1832, 256, 0, stream>>>(
        value, WtVf, b_v, v_f16, query, WtOAf, biasOA, oa_f32);
    sample_kernel<<<NQ / 4, 256, 0, stream>>>(v_f16, oa_f32, refp, mid);
    gemm_o_kernel<<<512, 256, 0, stream>>>(mid, WtOf, b_o, (float*)d_out);
}

// Round 10
// 182.782 us; speedup vs baseline: 1.8713x; 1.1572x over previous
//
#include <hip/hip_runtime.h>

#define NH 8
#define HD 32
#define SUMP 16
#define LQ 4096
#define BS 4
#define LV 8500
#define NQ (BS * LQ)   // 16384
#define MV (BS * LV)   // 34000

typedef float f32x4 __attribute__((ext_vector_type(4)));
typedef _Float16 f16x8 __attribute__((ext_vector_type(8)));

// ---------- prep: weights -> fp16 fragment-linear; bias concat ----------
// frag-linear: unit block (T = n>>4, C = k>>5) of 512 fp16 at offset (T*8+C)*512;
// within: lane16 = (n&15) + 16*((k>>3)&3) at lane16*8, elem = k&7.
__global__ __launch_bounds__(256) void prep_kernel(
    const float* __restrict__ Wv, const float* __restrict__ Woff,
    const float* __restrict__ Wattn, const float* __restrict__ Wo,
    const float* __restrict__ boff, const float* __restrict__ battn,
    _Float16* __restrict__ WtVf, _Float16* __restrict__ WtOAf,
    _Float16* __restrict__ WtOf, float* __restrict__ biasOA)
{
    int g = blockIdx.x * 256 + threadIdx.x;    // 0..229375
    int gl; _Float16* dst; int which;
    if (g < 65536)       { gl = g;          dst = WtVf;  which = 0; }
    else if (g < 163840) { gl = g - 65536;  dst = WtOAf; which = 1; }
    else                 { gl = g - 163840; dst = WtOf;  which = 2; }
    int e = gl & 7, m16 = (gl >> 3) & 15, q = (gl >> 7) & 3, C = (gl >> 9) & 7, T = gl >> 12;
    int n = T * 16 + m16, k = C * 32 + q * 8 + e;
    float w;
    if (which == 0)      w = Wv[k * 256 + n];
    else if (which == 1) w = (n < 256) ? Woff[k * 256 + n] : Wattn[k * 128 + (n - 256)];
    else                 w = Wo[k * 256 + n];
    dst[gl] = (_Float16)w;
    if (blockIdx.x == 0) biasOA[threadIdx.x] = boff[threadIdx.x];
    if (blockIdx.x == 1 && threadIdx.x < 128) biasOA[256 + threadIdx.x] = battn[threadIdx.x];
}

// ---------- GEMM: LDS-A (XOR swizzle) + frag-linear global B ----------
// Block 128 x (NI*32), 4 waves 2x2, wave tile 64 x (NI*16), K=256, BK=32, fp16 MFMA.
template <int NI, bool V_MODE, bool A_F16>
__device__ __forceinline__ void gemm_body(
    const float* __restrict__ A32, const _Float16* __restrict__ A16,
    const _Float16* __restrict__ Bf,
    const float* __restrict__ bias, void* __restrict__ Cv,
    int M, int N, int mb, int nb, _Float16* As /* 2*4096 fp16 */)
{
    const int t = threadIdx.x;
    const int wave = t >> 6, lane = t & 63;
    const int quad = lane >> 4, l16 = lane & 15;
    const int mbase = mb * 128 + (wave & 1) * 64;
    const int ntile0 = nb * (2 * NI) + (wave >> 1) * NI;

    const int srow = t >> 2, skq = t & 3;
    int gm0 = mb * 128 + srow;        if (gm0 > M - 1) gm0 = M - 1;
    int gm1 = mb * 128 + srow + 64;   if (gm1 > M - 1) gm1 = M - 1;
    const float* ap0 = A32 ? A32 + (size_t)gm0 * 256 + skq * 8 : nullptr;
    const float* ap1 = A32 ? A32 + (size_t)gm1 * 256 + skq * 8 : nullptr;
    const _Float16* hp0 = A16 ? A16 + (size_t)gm0 * 256 + skq * 8 : nullptr;
    const _Float16* hp1 = A16 ? A16 + (size_t)gm1 * 256 + skq * 8 : nullptr;
    const int slot0 = (((srow >> 4)) * 64 + skq * 16 + ((srow & 15) ^ skq)) * 8;
    const int slot1 = ((((srow + 64) >> 4)) * 64 + skq * 16 + ((srow & 15) ^ skq)) * 8;

    const _Float16* bp[NI];
    #pragma unroll
    for (int ni = 0; ni < NI; ++ni)
        bp[ni] = Bf + (size_t)(ntile0 + ni) * 4096 + lane * 8;

    float a0[8], a1[8];
    f16x8 a0h, a1h;
    f16x8 bcur[NI], bnxt[NI];
    f32x4 acc[4][NI] = {};

    if (A_F16) {
        a0h = *(const f16x8*)(hp0);
        a1h = *(const f16x8*)(hp1);
    } else {
        *(float4*)(a0 + 0) = *(const float4*)(ap0 + 0);
        *(float4*)(a0 + 4) = *(const float4*)(ap0 + 4);
        *(float4*)(a1 + 0) = *(const float4*)(ap1 + 0);
        *(float4*)(a1 + 4) = *(const float4*)(ap1 + 4);
    }
    #pragma unroll
    for (int ni = 0; ni < NI; ++ni) bcur[ni] = *(const f16x8*)(bp[ni]);

    #pragma unroll
    for (int k = 0; k < 8; ++k) {
        _Float16* buf = As + (k & 1) * 4096;
        f16x8 c0, c1;
        if (A_F16) { c0 = a0h; c1 = a1h; }
        else {
            #pragma unroll
            for (int j = 0; j < 8; ++j) { c0[j] = (_Float16)a0[j]; c1[j] = (_Float16)a1[j]; }
        }
        *(f16x8*)(buf + slot0) = c0;
        *(f16x8*)(buf + slot1) = c1;
        __syncthreads();
        if (k < 7) {
            const int k0 = (k + 1) * 32;
            if (A_F16) {
                a0h = *(const f16x8*)(hp0 + k0);
                a1h = *(const f16x8*)(hp1 + k0);
            } else {
                *(float4*)(a0 + 0) = *(const float4*)(ap0 + k0);
                *(float4*)(a0 + 4) = *(const float4*)(ap0 + k0 + 4);
                *(float4*)(a1 + 0) = *(const float4*)(ap1 + k0);
                *(float4*)(a1 + 4) = *(const float4*)(ap1 + k0 + 4);
            }
            #pragma unroll
            for (int ni = 0; ni < NI; ++ni) bnxt[ni] = *(const f16x8*)(bp[ni] + (k + 1) * 512);
        }
        f16x8 af[4];
        #pragma unroll
        for (int mi = 0; mi < 4; ++mi)
            af[mi] = *(const f16x8*)(buf + (((wave & 1) * 4 + mi) * 64 + quad * 16 + (l16 ^ quad)) * 8);
        #pragma unroll
        for (int mi = 0; mi < 4; ++mi)
            #pragma unroll
            for (int ni = 0; ni < NI; ++ni)
                acc[mi][ni] = __builtin_amdgcn_mfma_f32_16x16x32_f16(af[mi], bcur[ni], acc[mi][ni], 0, 0, 0);
        #pragma unroll
        for (int ni = 0; ni < NI; ++ni) bcur[ni] = bnxt[ni];
    }

    // epilogue: C/D col = l16, row = quad*4+r
    if (V_MODE) {
        #pragma unroll
        for (int mi = 0; mi < 4; ++mi) {
            int mq = mbase + mi * 16 + quad * 4;
            size_t rb[4]; int vld[4];
            #pragma unroll
            for (int r = 0; r < 4; ++r) {
                int m = mq + r;
                vld[r] = (m < M);
                int b = m / LV; int pos = m - b * LV;
                rb[r] = ((size_t)b * NH * LV + pos) * 32;
            }
            #pragma unroll
            for (int ni = 0; ni < NI; ++ni) {
                int n = (ntile0 + ni) * 16 + l16;
                float bv = bias[n];
                int h = n >> 5, d = n & 31;
                size_t ho = (size_t)h * (LV * 32) + d;
                #pragma unroll
                for (int r = 0; r < 4; ++r)
                    if (vld[r]) ((_Float16*)Cv)[rb[r] + ho] = (_Float16)(acc[mi][ni][r] + bv);
            }
        }
    } else {
        #pragma unroll
        for (int ni = 0; ni < NI; ++ni) {
            int n = (ntile0 + ni) * 16 + l16;
            float bv = bias[n];
            #pragma unroll
            for (int mi = 0; mi < 4; ++mi) {
                int mq = mbase + mi * 16 + quad * 4;
                #pragma unroll
                for (int r = 0; r < 4; ++r)
                    ((float*)Cv)[(size_t)(mq + r) * N + n] = acc[mi][ni][r] + bv;
            }
        }
    }
}

__global__ __launch_bounds__(256) void gemm_dual_kernel(
    const float* __restrict__ value, const _Float16* __restrict__ WtVf,
    const float* __restrict__ b_v, _Float16* __restrict__ v_f16,
    const float* __restrict__ query, const _Float16* __restrict__ WtOAf,
    const float* __restrict__ biasOA, float* __restrict__ oa)
{
    __shared__ __align__(16) _Float16 As[2 * 4096];
    int bid = blockIdx.x;
    if (bid < 1064) {         // V: 266 mb x 4 nb (tile 128x64)
        gemm_body<2, true, false>(value, nullptr, WtVf, b_v, v_f16, MV, 256,
                                  bid % 266, bid / 266, As);
    } else {                  // OA: 128 mb x 6 nb (tile 128x64)
        int q = bid - 1064;
        gemm_body<2, false, false>(query, nullptr, WtOAf, biasOA, oa, NQ, 384,
                                   q % 128, q / 128, As);
    }
}

__global__ __launch_bounds__(256) void gemm_o_kernel(
    const _Float16* __restrict__ mid, const _Float16* __restrict__ WtOf,
    const float* __restrict__ b_o, float* __restrict__ out)
{
    __shared__ __align__(16) _Float16 As[2 * 4096];
    gemm_body<2, false, true>(nullptr, mid, WtOf, b_o, out, NQ, 256,
                              blockIdx.x & 127, blockIdx.x >> 7, As);
}

// ---------- sampling: gather-only, 2 waves/query, 4 points/lane (no spill) ----------
// QPB=2 (8192 blocks). Query served by 2 waves; within a wave lane = pgl(1b)|h(3b)|dv2(2b);
// point p = (waveparity*2 + pgl)*4 + j. 16 in-flight 16B loads/lane (64 VGPR data).
// NO __launch_bounds__ VGPR cap: R7 (256,6) -> 550MB spill; R8 (256,4) -> 104MB spill.
__global__ void sample_kernel(
    const _Float16* __restrict__ v,          // [b][h][LV][32] fp16
    const float* __restrict__ oa,            // [NQ][384]: 0..255 offsets, 256..383 logits
    const float* __restrict__ refp,          // [NQ][4]
    _Float16* __restrict__ mid)              // [NQ][256] fp16
{
    const int row0 = blockIdx.x * 2;
    const int t = threadIdx.x;
    const int wave = t >> 6, lane = t & 63;

    __shared__ __align__(16) char smem[8704];
    float*  s_lx  = (float*)smem;                 // [2][128]  (union A: 3072 B)
    float*  s_ly  = (float*)(smem + 1024);
    float*  s_raw = (float*)(smem + 2048);
    int2*   s_pk  = (int2*)smem;                  // [2*8][17] (union B: 6528 B)
    float4* s_w4  = (float4*)(smem + 2176);
    float*  s_mx  = (float*)(smem + 6528);        // [16]
    float*  s_is  = (float*)(smem + 6592);        // [16]
    float*  s_part = (float*)(smem + 6656);       // [2][8][32] dword-transposed partials

    // --- P1: locations + raw logits (256 entries, 1/thread) ---
    {
        int q = t >> 7, e = t & 127;          // e = h*16 + p
        int row = row0 + q;
        float4 r4 = *(const float4*)(refp + (size_t)row * 4);
        float2 o2 = *(const float2*)(oa + (size_t)row * 384 + e * 2);
        s_lx[q * 128 + e]  = r4.x + o2.x * 0.125f * r4.z;
        s_ly[q * 128 + e]  = r4.y + o2.y * 0.125f * r4.w;
        s_raw[q * 128 + e] = oa[(size_t)row * 384 + 256 + e];
    }
    __syncthreads();
    // --- P2: softmax stats, one (q,h) per thread ---
    if (t < 16) {
        int q = t >> 3, h = t & 7;
        float mx = -1e30f;
        #pragma unroll
        for (int p = 0; p < SUMP; ++p) mx = fmaxf(mx, s_raw[q * 128 + h * 16 + p]);
        float sm = 0.f;
        #pragma unroll
        for (int p = 0; p < SUMP; ++p) sm += __expf(s_raw[q * 128 + h * 16 + p] - mx);
        s_mx[t] = mx; s_is[t] = 1.f / sm;
    }
    __syncthreads();
    // --- P3: corner weights + packed offsets to regs, then overlay store ---
    int2 r_pk;
    float4 r_w4;
    {
        int q = t >> 7, e = t & 127, h = e >> 4, p = e & 15, l = p >> 2;
        int Wl = 80 >> l;
        int vst = (l == 0) ? 0 : (l == 1) ? 6400 : (l == 2) ? 8000 : 8400;
        float w = __expf(s_raw[q * 128 + e] - s_mx[q * 8 + h]) * s_is[q * 8 + h];
        float x = s_lx[q * 128 + e] * Wl - 0.5f;
        float y = s_ly[q * 128 + e] * Wl - 0.5f;
        float x0f = floorf(x), y0f = floorf(y);
        float lx = x - x0f, ly = y - y0f;
        int x0 = (int)x0f, y0 = (int)y0f;
        int x1 = x0 + 1, y1 = y0 + 1;
        float mx0 = (x0 >= 0 && x0 < Wl) ? 1.f : 0.f;
        float mx1 = (x1 >= 0 && x1 < Wl) ? 1.f : 0.f;
        float my0 = (y0 >= 0 && y0 < Wl) ? 1.f : 0.f;
        float my1 = (y1 >= 0 && y1 < Wl) ? 1.f : 0.f;
        int cx0 = min(max(x0, 0), Wl - 1), cx1 = min(max(x1, 0), Wl - 1);
        int cy0 = min(max(y0, 0), Wl - 1), cy1 = min(max(y1, 0), Wl - 1);
        r_pk.x = (vst + cy0 * Wl + cx0) * 64;
        r_pk.y = ((cx1 - cx0) * 64) | (((cy1 - cy0) * Wl * 64) << 16);
        r_w4.x = w * (1.f - lx) * (1.f - ly) * mx0 * my0;
        r_w4.y = w * lx * (1.f - ly) * mx1 * my0;
        r_w4.z = w * (1.f - lx) * ly * mx0 * my1;
        r_w4.w = w * lx * ly * mx1 * my1;
    }
    __syncthreads();   // union-A reads done before overlay write
    {
        int q = t >> 7, e = t & 127, h = e >> 4, p = e & 15;
        int s = (q * 8 + h) * 17 + p;
        s_pk[s] = r_pk; s_w4[s] = r_w4;
    }
    __syncthreads();
    // --- P4: gather. q = wave>>1, wp = wave&1; lane = pgl|h|dv2; 4 points/lane ---
    {
        const int q = wave >> 1, wp = wave & 1;
        const int pgl = lane >> 5, hh = (lane >> 2) & 7, dv2 = lane & 3;
        const int row = row0 + q;
        const int b = row >> 12;              // LQ = 4096
        const char* vb = (const char*)v + ((size_t)(b * NH + hh) * LV) * 64 + dv2 * 16;
        float acc8[8] = {};
        #pragma unroll
        for (int j = 0; j < 4; ++j) {
            int p = (wp * 2 + pgl) * 4 + j;
            int s = (q * 8 + hh) * 17 + p;
            int2 pk = s_pk[s];
            float4 w4 = s_w4[s];
            int dx = pk.y & 0xffff, dy = pk.y >> 16;
            f16x8 g00 = *(const f16x8*)(vb + pk.x);
            f16x8 g01 = *(const f16x8*)(vb + pk.x + dx);
            f16x8 g10 = *(const f16x8*)(vb + pk.x + dy);
            f16x8 g11 = *(const f16x8*)(vb + pk.x + dx + dy);
            #pragma unroll
            for (int c = 0; c < 8; ++c)
                acc8[c] += w4.x * (float)g00[c] + w4.y * (float)g01[c]
                         + w4.z * (float)g10[c] + w4.w * (float)g11[c];
        }
        // combine pgl halves within wave
        #pragma unroll
        for (int c = 0; c < 8; ++c) acc8[c] += __shfl_xor(acc8[c], 32, 64);
        // cross-wave combine via LDS (dword-transposed: conflict-free)
        if (wp == 1 && lane < 32) {
            #pragma unroll
            for (int c = 0; c < 8; ++c) s_part[q * 256 + c * 32 + lane] = acc8[c];
        }
        __syncthreads();
        if (wp == 0 && lane < 32) {
            f16x8 m8;
            #pragma unroll
            for (int c = 0; c < 8; ++c)
                m8[c] = (_Float16)(acc8[c] + s_part[q * 256 + c * 32 + lane]);
            *(f16x8*)(mid + (size_t)row * 256 + hh * 32 + dv2 * 8) = m8;
        }
    }
}

extern "C" void kernel_launch(void* const* d_in, const int* in_sizes, int n_in,
                              void* d_out, int out_size, void* d_ws, size_t ws_size,
                              hipStream_t stream) {
    const float* query  = (const float*)d_in[0];   // [4,4096,256]
    const float* refp   = (const float*)d_in[1];   // [4,4096,1,4]
    const float* value  = (const float*)d_in[2];   // [4,8500,256]
    const float* W_off  = (const float*)d_in[3];   // [256,256]
    const float* b_off  = (const float*)d_in[4];   // [256]
    const float* W_attn = (const float*)d_in[5];   // [256,128]
    const float* b_attn = (const float*)d_in[6];   // [128]
    const float* W_v    = (const float*)d_in[7];   // [256,256]
    const float* b_v    = (const float*)d_in[8];   // [256]
    const float* W_o    = (const float*)d_in[9];   // [256,256]
    const float* b_o    = (const float*)d_in[10];  // [256]

    char* ws = (char*)d_ws;
    _Float16* v_f16  = (_Float16*)(ws + 0);               // 17,408,000 B
    float*    oa_f32 = (float*)(ws + 17408000);           // 25,165,824 B
    _Float16* mid    = (_Float16*)(ws + 42573824);        //  8,388,608 B
    _Float16* WtVf   = (_Float16*)(ws + 50962432);        //    131,072 B
    _Float16* WtOAf  = (_Float16*)(ws + 51093504);        //    196,608 B
    _Float16* WtOf   = (_Float16*)(ws + 51290112);        //    131,072 B
    float*    biasOA = (float*)(ws + 51421184);           //      1,536 B

    prep_kernel<<<896, 256, 0, stream>>>(W_v, W_off, W_attn, W_o, b_off, b_attn,
                                         WtVf, WtOAf, WtOf, biasOA);
    gemm_dual_kernel<<<1832, 256, 0, stream>>>(
        value, WtVf, b_v, v_f16, query, WtOAf, biasOA, oa_f32);
    sample_kernel<<<NQ / 2, 256, 0, stream>>>(v_f16, oa_f32, refp, mid);
    gemm_o_kernel<<<512, 256, 0, stream>>>(mid, WtOf, b_o, (float*)d_out);
}